// Round 17
// baseline (29.601 us; speedup 1.0000x reference)
//
#include <hip/hip_runtime.h>

#define T_DIM 1024
#define B_DIM 32
#define C_DIM 512
#define PROWS 64   // R12/R15-validated: 512 blocks, 2 per CU

typedef float f32x4 __attribute__((ext_vector_type(4)));

// R15 skeleton, single change: nontemporal loads+stores on the audio stream
// (L2-bypass; video/labels/sscale stay cached).
__global__ __launch_bounds__(256) void k_fused(const float* __restrict__ video,
                                               const float* __restrict__ audio,
                                               const int* __restrict__ labels,
                                               float* __restrict__ out) {
    int b     = blockIdx.y;
    int pBase = blockIdx.x * PROWS;
    int tid   = threadIdx.x;
    int lane  = tid & 63;
    int wave  = tid >> 6;
    __shared__ float vm[T_DIM];
    __shared__ int   pos[T_DIM];
    __shared__ int   waveTot[4];
    __shared__ float sscale[PROWS];

    // streaming geometry: thread handles rows k = 2*i + half, i = 0..31
    int half = tid >> 7;
    int c4   = tid & 127;
    const int rstep = 2 * B_DIM * (C_DIM / 4);
    int base0 = ((pBase + half) * B_DIM + b) * (C_DIM / 4) + c4;
    const f32x4* ain  = (const f32x4*)audio;
    f32x4*       aout = (f32x4*)out;

    // ---- phase A: prefetch first 2 audio rows (NT) + labels together ----
    f32x4 a[32];
    a[0] = __builtin_nontemporal_load(ain + base0);
    a[1] = __builtin_nontemporal_load(ain + base0 + rstep);
    int4 lv = *(const int4*)(labels + b * T_DIM + tid * 4);

    int p0 = tid * 4;
    int f0 = (lv.x == 1), f1 = (lv.y == 1), f2 = (lv.z == 1), f3 = (lv.w == 1);
    int cnt = f0 + f1 + f2 + f3;

    int incl = cnt;
    #pragma unroll
    for (int off = 1; off < 64; off <<= 1) {
        int n = __shfl_up(incl, off);
        if (lane >= off) incl += n;
    }
    if (lane == 63) waveTot[wave] = incl;
    __syncthreads();

    int waveOff = 0;
    for (int w = 0; w < wave; ++w) waveOff += waveTot[w];
    int t = waveTot[0] + waveTot[1] + waveTot[2] + waveTot[3];
    int r = waveOff + incl - cnt;

    if (f0) pos[r++] = p0 + 0;
    if (f1) pos[r++] = p0 + 1;
    if (f2) pos[r++] = p0 + 2;
    if (f3) pos[r++] = p0 + 3;
    __syncthreads();

    // ---- phase B: means, 4 rows per wave per round (1 round for t<=16) ----
    for (int base = 0; base < t; base += 16) {
        int rr0 = base + wave;
        int rr1 = rr0 + 4, rr2 = rr0 + 8, rr3 = rr0 + 12;
        int rc0 = rr0 < t ? rr0 : 0;
        int rc1 = rr1 < t ? rr1 : 0;
        int rc2 = rr2 < t ? rr2 : 0;
        int rc3 = rr3 < t ? rr3 : 0;
        const float* s0p = video + (size_t)pos[rc0] * (B_DIM * C_DIM) + b * C_DIM;
        const float* s1p = video + (size_t)pos[rc1] * (B_DIM * C_DIM) + b * C_DIM;
        const float* s2p = video + (size_t)pos[rc2] * (B_DIM * C_DIM) + b * C_DIM;
        const float* s3p = video + (size_t)pos[rc3] * (B_DIM * C_DIM) + b * C_DIM;
        float4 x0a = *(const float4*)(s0p + lane * 4);
        float4 x0b = *(const float4*)(s0p + 256 + lane * 4);
        float4 x1a = *(const float4*)(s1p + lane * 4);
        float4 x1b = *(const float4*)(s1p + 256 + lane * 4);
        float4 x2a = *(const float4*)(s2p + lane * 4);
        float4 x2b = *(const float4*)(s2p + 256 + lane * 4);
        float4 x3a = *(const float4*)(s3p + lane * 4);
        float4 x3b = *(const float4*)(s3p + 256 + lane * 4);
        float v0 = x0a.x + x0a.y + x0a.z + x0a.w + x0b.x + x0b.y + x0b.z + x0b.w;
        float v1 = x1a.x + x1a.y + x1a.z + x1a.w + x1b.x + x1b.y + x1b.z + x1b.w;
        float v2 = x2a.x + x2a.y + x2a.z + x2a.w + x2b.x + x2b.y + x2b.z + x2b.w;
        float v3 = x3a.x + x3a.y + x3a.z + x3a.w + x3b.x + x3b.y + x3b.z + x3b.w;
        #pragma unroll
        for (int off = 32; off; off >>= 1) {
            v0 += __shfl_xor(v0, off);
            v1 += __shfl_xor(v1, off);
            v2 += __shfl_xor(v2, off);
            v3 += __shfl_xor(v3, off);
        }
        if (lane == 0) {
            if (rr0 < t) vm[rr0] = v0 * (1.0f / C_DIM);
            if (rr1 < t) vm[rr1] = v1 * (1.0f / C_DIM);
            if (rr2 < t) vm[rr2] = v2 * (1.0f / C_DIM);
            if (rr3 < t) vm[rr3] = v3 * (1.0f / C_DIM);
        }
    }
    __syncthreads();

    // ---- phase C: issue remaining 30 audio rows (NT), then product ----
    #pragma unroll
    for (int i = 2; i < 32; ++i)
        a[i] = __builtin_nontemporal_load(ain + base0 + i * rstep);

    if (tid < PROWS) {
        int p  = pBase + tid;
        int lo = p - (T_DIM - t); if (lo < 0) lo = 0;
        int hi = p < (t - 1) ? p : (t - 1);
        float s = 1.0f;
        for (int m = lo; m <= hi; ++m) s *= vm[m];
        sscale[tid] = s;
    }
    __syncthreads();

    // ---- phase D: mul + NT store burst ----
    #pragma unroll
    for (int i = 0; i < 32; ++i) {
        float s = sscale[2 * i + half];
        __builtin_nontemporal_store(a[i] * s, aout + base0 + i * rstep);
    }
}

extern "C" void kernel_launch(void* const* d_in, const int* in_sizes, int n_in,
                              void* d_out, int out_size, void* d_ws, size_t ws_size,
                              hipStream_t stream) {
    const float* video  = (const float*)d_in[0];
    const float* audio  = (const float*)d_in[1];
    const int*   labels = (const int*)d_in[2];
    float* out = (float*)d_out;

    dim3 grid(T_DIM / PROWS, B_DIM);
    k_fused<<<grid, 256, 0, stream>>>(video, audio, labels, out);
}

// Round 18
// 26.510 us; speedup vs baseline: 1.1166x; 1.1166x over previous
//
#include <hip/hip_runtime.h>

#define T_DIM 1024
#define B_DIM 32
#define C_DIM 512
#define PROWS 64   // best-known (R12/R15): 512 blocks, 2 per CU

typedef float f32x4 __attribute__((ext_vector_type(4)));

// R15 (best known, 26.69 us): R12 skeleton + one-round means.
//   A: prefetch first 2 audio rows + labels; block-scan compaction
//   B: means, 4 rows per wave per round (1 round for t<=16)
//   C: issue remaining 30 audio rows; 64-thread serial windowed product
//   D: mul + store burst
__global__ __launch_bounds__(256) void k_fused(const float* __restrict__ video,
                                               const float* __restrict__ audio,
                                               const int* __restrict__ labels,
                                               float* __restrict__ out) {
    int b     = blockIdx.y;
    int pBase = blockIdx.x * PROWS;
    int tid   = threadIdx.x;
    int lane  = tid & 63;
    int wave  = tid >> 6;
    __shared__ float vm[T_DIM];
    __shared__ int   pos[T_DIM];
    __shared__ int   waveTot[4];
    __shared__ float sscale[PROWS];

    // streaming geometry: thread handles rows k = 2*i + half, i = 0..31
    int half = tid >> 7;
    int c4   = tid & 127;
    const int rstep = 2 * B_DIM * (C_DIM / 4);
    int base0 = ((pBase + half) * B_DIM + b) * (C_DIM / 4) + c4;
    const f32x4* ain  = (const f32x4*)audio;
    f32x4*       aout = (f32x4*)out;

    // ---- phase A: prefetch first 2 audio rows + labels together ----
    f32x4 a[32];
    a[0] = ain[base0];
    a[1] = ain[base0 + rstep];
    int4 lv = *(const int4*)(labels + b * T_DIM + tid * 4);

    int p0 = tid * 4;
    int f0 = (lv.x == 1), f1 = (lv.y == 1), f2 = (lv.z == 1), f3 = (lv.w == 1);
    int cnt = f0 + f1 + f2 + f3;

    int incl = cnt;
    #pragma unroll
    for (int off = 1; off < 64; off <<= 1) {
        int n = __shfl_up(incl, off);
        if (lane >= off) incl += n;
    }
    if (lane == 63) waveTot[wave] = incl;
    __syncthreads();

    int waveOff = 0;
    for (int w = 0; w < wave; ++w) waveOff += waveTot[w];
    int t = waveTot[0] + waveTot[1] + waveTot[2] + waveTot[3];
    int r = waveOff + incl - cnt;

    if (f0) pos[r++] = p0 + 0;
    if (f1) pos[r++] = p0 + 1;
    if (f2) pos[r++] = p0 + 2;
    if (f3) pos[r++] = p0 + 3;
    __syncthreads();

    // ---- phase B: means, 4 rows per wave per round (1 round for t<=16) ----
    for (int base = 0; base < t; base += 16) {
        int rr0 = base + wave;
        int rr1 = rr0 + 4, rr2 = rr0 + 8, rr3 = rr0 + 12;
        int rc0 = rr0 < t ? rr0 : 0;
        int rc1 = rr1 < t ? rr1 : 0;
        int rc2 = rr2 < t ? rr2 : 0;
        int rc3 = rr3 < t ? rr3 : 0;
        const float* s0p = video + (size_t)pos[rc0] * (B_DIM * C_DIM) + b * C_DIM;
        const float* s1p = video + (size_t)pos[rc1] * (B_DIM * C_DIM) + b * C_DIM;
        const float* s2p = video + (size_t)pos[rc2] * (B_DIM * C_DIM) + b * C_DIM;
        const float* s3p = video + (size_t)pos[rc3] * (B_DIM * C_DIM) + b * C_DIM;
        float4 x0a = *(const float4*)(s0p + lane * 4);
        float4 x0b = *(const float4*)(s0p + 256 + lane * 4);
        float4 x1a = *(const float4*)(s1p + lane * 4);
        float4 x1b = *(const float4*)(s1p + 256 + lane * 4);
        float4 x2a = *(const float4*)(s2p + lane * 4);
        float4 x2b = *(const float4*)(s2p + 256 + lane * 4);
        float4 x3a = *(const float4*)(s3p + lane * 4);
        float4 x3b = *(const float4*)(s3p + 256 + lane * 4);
        float v0 = x0a.x + x0a.y + x0a.z + x0a.w + x0b.x + x0b.y + x0b.z + x0b.w;
        float v1 = x1a.x + x1a.y + x1a.z + x1a.w + x1b.x + x1b.y + x1b.z + x1b.w;
        float v2 = x2a.x + x2a.y + x2a.z + x2a.w + x2b.x + x2b.y + x2b.z + x2b.w;
        float v3 = x3a.x + x3a.y + x3a.z + x3a.w + x3b.x + x3b.y + x3b.z + x3b.w;
        #pragma unroll
        for (int off = 32; off; off >>= 1) {
            v0 += __shfl_xor(v0, off);
            v1 += __shfl_xor(v1, off);
            v2 += __shfl_xor(v2, off);
            v3 += __shfl_xor(v3, off);
        }
        if (lane == 0) {
            if (rr0 < t) vm[rr0] = v0 * (1.0f / C_DIM);
            if (rr1 < t) vm[rr1] = v1 * (1.0f / C_DIM);
            if (rr2 < t) vm[rr2] = v2 * (1.0f / C_DIM);
            if (rr3 < t) vm[rr3] = v3 * (1.0f / C_DIM);
        }
    }
    __syncthreads();

    // ---- phase C: issue remaining 30 audio rows, then windowed product ----
    #pragma unroll
    for (int i = 2; i < 32; ++i)
        a[i] = ain[base0 + i * rstep];

    if (tid < PROWS) {
        int p  = pBase + tid;
        int lo = p - (T_DIM - t); if (lo < 0) lo = 0;
        int hi = p < (t - 1) ? p : (t - 1);
        float s = 1.0f;
        for (int m = lo; m <= hi; ++m) s *= vm[m];
        sscale[tid] = s;
    }
    __syncthreads();

    // ---- phase D: mul + store burst ----
    #pragma unroll
    for (int i = 0; i < 32; ++i) {
        float s = sscale[2 * i + half];
        aout[base0 + i * rstep] = a[i] * s;
    }
}

extern "C" void kernel_launch(void* const* d_in, const int* in_sizes, int n_in,
                              void* d_out, int out_size, void* d_ws, size_t ws_size,
                              hipStream_t stream) {
    const float* video  = (const float*)d_in[0];
    const float* audio  = (const float*)d_in[1];
    const int*   labels = (const int*)d_in[2];
    float* out = (float*)d_out;

    dim3 grid(T_DIM / PROWS, B_DIM);
    k_fused<<<grid, 256, 0, stream>>>(video, audio, labels, out);
}